// Round 1
// baseline (308.456 us; speedup 1.0000x reference)
//
#include <hip/hip_runtime.h>
#include <cstddef>

// ---------------------------------------------------------------------------
// LinearAttention fused pipeline (fp32 baseline, round 0)
//
// y = rmsnorm( w_out @ ( ctx^T per-head @ (softmax_d(q)*SCALE) ) + b, g2 )
//   where ctx[h,d,e] = (sum_n exp(k[h,d,n]) v[h,e,n] + mem terms)
//                      / (sum_n exp(k[h,d,n]) + mem terms)
//   and q,k,v = (w_qkv * (g1+1)*sqrt(128)) @ (x * rsqrt(sum_c x^2))
//
// Softmax global-max subtractions in the reference are shift-invariant -> dropped.
// SCALE and w_out and ctx are folded into W2 (128x128), so the back half is
// one GEMM. qkv is never materialized in HBM.
// ---------------------------------------------------------------------------

static constexpr int   NTOK = 65536;                 // H*W
static constexpr float NORM_SCALE_F = 11.313708498984761f; // sqrt(128)
static constexpr float SCALE_F      = 0.17677669529663687f; // 1/sqrt(32)
static constexpr int   NB1 = 256;                    // k1 block count

// ---------------------------------------------------------------- K0: fold
// wT[c][o] = w_qkv[o][c] * (gamma1[c]+1) * sqrt(128);  layout [128][384]
__global__ __launch_bounds__(256) void k0_fold(const float* __restrict__ w_qkv,
                                               const float* __restrict__ gamma1,
                                               float* __restrict__ wT) {
  const int id = blockIdx.x * 256 + threadIdx.x;   // < 49152 = 384*128
  const int o = id % 384;
  const int c = id / 384;
  wT[c * 384 + o] = w_qkv[o * 128 + c] * (gamma1[c] + 1.0f) * NORM_SCALE_F;
}

// shared 64x64x128 fp32 GEMM micro-kernel: two 64-row chunks (A,B) x 64 tokens.
// thread map: to = t>>3 (32 row-pairs), tn = t&7 (8 col-octets); 2x8 per chunk.
__device__ __forceinline__ void gemm_pair(const float* __restrict__ bA,
                                          const float* __restrict__ bB,
                                          const float* __restrict__ bX,
                                          int to, int tn, float (&a)[2][2][8]) {
  #pragma unroll 8
  for (int c = 0; c < 128; ++c) {
    const float2 wa = *reinterpret_cast<const float2*>(&bA[c * 68 + to * 2]);
    const float2 wb = *reinterpret_cast<const float2*>(&bB[c * 68 + to * 2]);
    const float4 x0 = *reinterpret_cast<const float4*>(&bX[c * 68 + tn * 8]);
    const float4 x1 = *reinterpret_cast<const float4*>(&bX[c * 68 + tn * 8 + 4]);
    const float xv[8] = {x0.x, x0.y, x0.z, x0.w, x1.x, x1.y, x1.z, x1.w};
    #pragma unroll
    for (int j = 0; j < 8; ++j) {
      a[0][0][j] += wa.x * xv[j];
      a[0][1][j] += wa.y * xv[j];
      a[1][0][j] += wb.x * xv[j];
      a[1][1][j] += wb.y * xv[j];
    }
  }
}

// ---------------------------------------------------------------- K1:
// per 64-token tile: stage x, per-token rsqrt(sumsq), k/v GEMM (256 rows),
// exp(k), accumulate per-block context partials C[h][d][e], S[h][d].
__global__ __launch_bounds__(256) void k1_kv(const float* __restrict__ x,
                                             const float* __restrict__ wT,
                                             float* __restrict__ Cp,
                                             float* __restrict__ Sp) {
  __shared__ float bufX[128 * 68];   // x tile [c][n], pad 68
  __shared__ float bufA[128 * 68];   // weight chunk / later vT [n][132]
  __shared__ float bufB[128 * 68];   // weight chunk
  __shared__ float bufC[64 * 132];   // keT [n][row]
  __shared__ float scn[64];          // per-token rsqrt(sumsq)
  __shared__ float redn[16 * 68];    // norm reduction

  const int t   = threadIdx.x;
  const int bid = blockIdx.x;
  const int sr  = t >> 4, scc = t & 15;            // staging map
  const int to  = t >> 3, tn  = t & 7;             // GEMM map
  const int h   = t >> 6, rem = t & 63;            // context map
  const int dp  = rem >> 3, ep = rem & 7;

  float Cacc[4][4] = {};
  float Sacc[4] = {};

  for (int tile = 0; tile < 4; ++tile) {
    const int n0 = (bid * 4 + tile) * 64;
    __syncthreads();   // prev-tile context reads done; buffers reusable

    // ---- stage x + column sum-of-squares
    float q0 = 0.f, q1 = 0.f, q2 = 0.f, q3 = 0.f;
    #pragma unroll
    for (int i = 0; i < 8; ++i) {
      const int c = i * 16 + sr;
      const float4 v = *reinterpret_cast<const float4*>(x + (size_t)c * NTOK + n0 + scc * 4);
      *reinterpret_cast<float4*>(&bufX[c * 68 + scc * 4]) = v;
      q0 += v.x * v.x; q1 += v.y * v.y; q2 += v.z * v.z; q3 += v.w * v.w;
    }
    *reinterpret_cast<float4*>(&redn[sr * 68 + scc * 4]) = make_float4(q0, q1, q2, q3);
    __syncthreads();
    if (t < 64) {
      float s = 0.f;
      #pragma unroll
      for (int g = 0; g < 16; ++g) s += redn[g * 68 + t];
      scn[t] = rsqrtf(s);
    }
    // ---- stage k-weight pair (qkv rows 128..191 -> A, 192..255 -> B)
    #pragma unroll
    for (int i = 0; i < 8; ++i) {
      const int c = i * 16 + sr;
      *reinterpret_cast<float4*>(&bufA[c * 68 + scc * 4]) =
          *reinterpret_cast<const float4*>(wT + c * 384 + 128 + scc * 4);
      *reinterpret_cast<float4*>(&bufB[c * 68 + scc * 4]) =
          *reinterpret_cast<const float4*>(wT + c * 384 + 192 + scc * 4);
    }
    __syncthreads();

    float ak[2][2][8] = {};
    gemm_pair(bufA, bufB, bufX, to, tn, ak);
    __syncthreads();   // GEMM reads of A/B done

    float sv[8];
    #pragma unroll
    for (int j = 0; j < 8; ++j) sv[j] = scn[tn * 8 + j];

    // keT[n][row] = exp(k * s[n])
    #pragma unroll
    for (int p = 0; p < 2; ++p)
      #pragma unroll
      for (int i = 0; i < 2; ++i) {
        const int row = p * 64 + to * 2 + i;
        #pragma unroll
        for (int j = 0; j < 8; ++j)
          bufC[(tn * 8 + j) * 132 + row] = __expf(ak[p][i][j] * sv[j]);
      }
    // stage v-weight pair (qkv rows 256..319 -> A, 320..383 -> B)
    #pragma unroll
    for (int i = 0; i < 8; ++i) {
      const int c = i * 16 + sr;
      *reinterpret_cast<float4*>(&bufA[c * 68 + scc * 4]) =
          *reinterpret_cast<const float4*>(wT + c * 384 + 256 + scc * 4);
      *reinterpret_cast<float4*>(&bufB[c * 68 + scc * 4]) =
          *reinterpret_cast<const float4*>(wT + c * 384 + 320 + scc * 4);
    }
    __syncthreads();

    float av[2][2][8] = {};
    gemm_pair(bufA, bufB, bufX, to, tn, av);
    __syncthreads();   // GEMM reads of A done -> reuse A for vT

    #pragma unroll
    for (int p = 0; p < 2; ++p)
      #pragma unroll
      for (int i = 0; i < 2; ++i) {
        const int row = p * 64 + to * 2 + i;
        #pragma unroll
        for (int j = 0; j < 8; ++j)
          bufA[(tn * 8 + j) * 132 + row] = av[p][i][j] * sv[j];
      }
    __syncthreads();   // keT + vT ready

    // ---- context partial accumulate: C[h][dp*4+i][ep*4+j] += ke * v
    #pragma unroll 4
    for (int n = 0; n < 64; ++n) {
      const float4 kq = *reinterpret_cast<const float4*>(&bufC[n * 132 + h * 32 + dp * 4]);
      const float4 vv = *reinterpret_cast<const float4*>(&bufA[n * 132 + h * 32 + ep * 4]);
      const float kk[4] = {kq.x, kq.y, kq.z, kq.w};
      const float vl[4] = {vv.x, vv.y, vv.z, vv.w};
      #pragma unroll
      for (int i = 0; i < 4; ++i)
        #pragma unroll
        for (int j = 0; j < 4; ++j)
          Cacc[i][j] += kk[i] * vl[j];
      if (ep == 0) {
        Sacc[0] += kk[0]; Sacc[1] += kk[1]; Sacc[2] += kk[2]; Sacc[3] += kk[3];
      }
    }
  }

  // ---- write per-block partials
  const int base = bid * 4096 + h * 1024;
  #pragma unroll
  for (int i = 0; i < 4; ++i)
    *reinterpret_cast<float4*>(Cp + base + (dp * 4 + i) * 32 + ep * 4) =
        make_float4(Cacc[i][0], Cacc[i][1], Cacc[i][2], Cacc[i][3]);
  if (ep == 0) {
    #pragma unroll
    for (int i = 0; i < 4; ++i) Sp[bid * 128 + h * 32 + dp * 4 + i] = Sacc[i];
  }
}

// ---------------------------------------------------------------- K3a:
// reduce partials over NB1 blocks in 8 chunks of 32. elems: 4096 C + 128 S.
__global__ __launch_bounds__(256) void k3a_reduce(const float* __restrict__ Cp,
                                                  const float* __restrict__ Sp,
                                                  float* __restrict__ Cpp) {
  __shared__ float red[256];
  const int t = threadIdx.x;
  const int eg = blockIdx.x;   // 0..32
  const int ch = blockIdx.y;   // 0..7
  const int e = eg * 128 + (t & 127);
  const int half = t >> 7;
  float s = 0.f;
  for (int bb = 0; bb < 16; ++bb) {
    const int b = ch * 32 + half * 16 + bb;
    s += (e < 4096) ? Cp[(size_t)b * 4096 + e] : Sp[b * 128 + (e - 4096)];
  }
  red[t] = s;
  __syncthreads();
  if (t < 128) Cpp[ch * 4224 + eg * 128 + t] = red[t] + red[t + 128];
}

// ---------------------------------------------------------------- K3b1:
// final reduce + memory-kv terms + divide -> ctx[4096]
__global__ __launch_bounds__(256) void k3b1_ctx(const float* __restrict__ Cpp,
                                                const float* __restrict__ mem_kv,
                                                float* __restrict__ ctx) {
  __shared__ float allv[4224];
  const int t = threadIdx.x;
  for (int e = t; e < 4224; e += 256) {
    float s = 0.f;
    #pragma unroll
    for (int c = 0; c < 8; ++c) s += Cpp[c * 4224 + e];
    allv[e] = s;
  }
  __syncthreads();
  for (int e = t; e < 4224; e += 256) {
    if (e < 4096) {
      const int hh = e >> 10, d = (e >> 5) & 31, ev = e & 31;
      float add = 0.f;
      #pragma unroll
      for (int m = 0; m < 4; ++m)
        add += __expf(mem_kv[(hh * 32 + d) * 4 + m]) * mem_kv[512 + (hh * 32 + ev) * 4 + m];
      allv[e] += add;
    } else {
      const int si = e - 4096;
      const int hh = si >> 5, d = si & 31;
      float add = 0.f;
      #pragma unroll
      for (int m = 0; m < 4; ++m) add += __expf(mem_kv[(hh * 32 + d) * 4 + m]);
      allv[e] += add;
    }
  }
  __syncthreads();
  for (int e = t; e < 4096; e += 256)
    ctx[e] = allv[e] / allv[4096 + (e >> 5)];
}

// ---------------------------------------------------------------- K3b2:
// W2T[hd][o] = SCALE * sum_e w_out[o][h*32+e] * ctx[h][d][e]
__global__ __launch_bounds__(256) void k3b2_w2(const float* __restrict__ ctx,
                                               const float* __restrict__ w_out,
                                               float* __restrict__ W2T) {
  const int t = threadIdx.x;
  const int hd = t & 127;
  const int og = t >> 7;
  const int hh = hd >> 5, d = hd & 31;
  const int bo = blockIdx.x;  // 0..7
  #pragma unroll
  for (int i = 0; i < 8; ++i) {
    const int o = bo * 16 + og * 8 + i;
    float s = 0.f;
    #pragma unroll
    for (int e = 0; e < 32; ++e)
      s += w_out[o * 128 + hh * 32 + e] * ctx[hh * 1024 + d * 32 + e];
    W2T[hd * 128 + o] = s * SCALE_F;
  }
}

// ---------------------------------------------------------------- K5:
// per 64-token tile: re-norm x, q GEMM, per-(head,token) softmax,
// z = W2 @ q_sm + b, rmsnorm(gamma2), store y.
__global__ __launch_bounds__(256) void k5_out(const float* __restrict__ x,
                                              const float* __restrict__ wT,
                                              const float* __restrict__ W2T,
                                              const float* __restrict__ b_out,
                                              const float* __restrict__ gamma2,
                                              float* __restrict__ y) {
  __shared__ float bufX[128 * 68];   // x tile, then q_raw / q_softmax
  __shared__ float bufA[128 * 68];
  __shared__ float bufB[128 * 68];
  __shared__ float red2[32 * 68];
  __shared__ float scn[64];
  __shared__ float rrn[64];

  const int t  = threadIdx.x;
  const int n0 = blockIdx.x * 64;
  const int sr = t >> 4, scc = t & 15;
  const int to = t >> 3, tn  = t & 7;
  const int h  = t >> 6;

  // ---- stage x + norm
  float q0 = 0.f, q1 = 0.f, q2 = 0.f, q3 = 0.f;
  #pragma unroll
  for (int i = 0; i < 8; ++i) {
    const int c = i * 16 + sr;
    const float4 v = *reinterpret_cast<const float4*>(x + (size_t)c * NTOK + n0 + scc * 4);
    *reinterpret_cast<float4*>(&bufX[c * 68 + scc * 4]) = v;
    q0 += v.x * v.x; q1 += v.y * v.y; q2 += v.z * v.z; q3 += v.w * v.w;
  }
  *reinterpret_cast<float4*>(&red2[sr * 68 + scc * 4]) = make_float4(q0, q1, q2, q3);
  __syncthreads();
  if (t < 64) {
    float s = 0.f;
    #pragma unroll
    for (int g = 0; g < 16; ++g) s += red2[g * 68 + t];
    scn[t] = rsqrtf(s);
  }
  // ---- stage q weights (qkv rows 0..63 -> A, 64..127 -> B)
  #pragma unroll
  for (int i = 0; i < 8; ++i) {
    const int c = i * 16 + sr;
    *reinterpret_cast<float4*>(&bufA[c * 68 + scc * 4]) =
        *reinterpret_cast<const float4*>(wT + c * 384 + 0 + scc * 4);
    *reinterpret_cast<float4*>(&bufB[c * 68 + scc * 4]) =
        *reinterpret_cast<const float4*>(wT + c * 384 + 64 + scc * 4);
  }
  __syncthreads();

  float aq[2][2][8] = {};
  gemm_pair(bufA, bufB, bufX, to, tn, aq);
  __syncthreads();   // all x reads done -> reuse bufX for q

  {
    float sv[8];
    #pragma unroll
    for (int j = 0; j < 8; ++j) sv[j] = scn[tn * 8 + j];
    #pragma unroll
    for (int p = 0; p < 2; ++p)
      #pragma unroll
      for (int i = 0; i < 2; ++i) {
        const int row = p * 64 + to * 2 + i;
        *reinterpret_cast<float4*>(&bufX[row * 68 + tn * 8]) =
            make_float4(aq[p][i][0] * sv[0], aq[p][i][1] * sv[1],
                        aq[p][i][2] * sv[2], aq[p][i][3] * sv[3]);
        *reinterpret_cast<float4*>(&bufX[row * 68 + tn * 8 + 4]) =
            make_float4(aq[p][i][4] * sv[4], aq[p][i][5] * sv[5],
                        aq[p][i][6] * sv[6], aq[p][i][7] * sv[7]);
      }
  }
  __syncthreads();

  // ---- softmax over d (32 rows) per (head = wave, token = lane)
  {
    const int n = t & 63;
    float ev[32];
    float ss = 0.f;
    #pragma unroll
    for (int d = 0; d < 32; ++d) {
      ev[d] = __expf(bufX[(h * 32 + d) * 68 + n]);
      ss += ev[d];
    }
    const float inv = 1.0f / ss;
    #pragma unroll
    for (int d = 0; d < 32; ++d) bufX[(h * 32 + d) * 68 + n] = ev[d] * inv;
  }
  __syncthreads();

  // ---- stage W2T chunks (o 0..63 -> A, 64..127 -> B)
  #pragma unroll
  for (int i = 0; i < 8; ++i) {
    const int c = i * 16 + sr;
    *reinterpret_cast<float4*>(&bufA[c * 68 + scc * 4]) =
        *reinterpret_cast<const float4*>(W2T + c * 128 + 0 + scc * 4);
    *reinterpret_cast<float4*>(&bufB[c * 68 + scc * 4]) =
        *reinterpret_cast<const float4*>(W2T + c * 128 + 64 + scc * 4);
  }
  __syncthreads();

  float az[2][2][8] = {};
  gemm_pair(bufA, bufB, bufX, to, tn, az);

  // ---- + bias, column sum-of-squares partials
  #pragma unroll
  for (int p = 0; p < 2; ++p)
    #pragma unroll
    for (int i = 0; i < 2; ++i) {
      const float bb = b_out[p * 64 + to * 2 + i];
      #pragma unroll
      for (int j = 0; j < 8; ++j) az[p][i][j] += bb;
    }
  float pp[8] = {};
  #pragma unroll
  for (int p = 0; p < 2; ++p)
    #pragma unroll
    for (int i = 0; i < 2; ++i)
      #pragma unroll
      for (int j = 0; j < 8; ++j) pp[j] += az[p][i][j] * az[p][i][j];

  *reinterpret_cast<float4*>(&red2[to * 68 + tn * 8]) = make_float4(pp[0], pp[1], pp[2], pp[3]);
  *reinterpret_cast<float4*>(&red2[to * 68 + tn * 8 + 4]) = make_float4(pp[4], pp[5], pp[6], pp[7]);
  __syncthreads();
  if (t < 64) {
    float s = 0.f;
    #pragma unroll
    for (int g = 0; g < 32; ++g) s += red2[g * 68 + t];
    rrn[t] = rsqrtf(s);
  }
  __syncthreads();

  // ---- write y = z * rsqrt(sum z^2) * (g2+1)*sqrt(128)
  float rv[8];
  #pragma unroll
  for (int j = 0; j < 8; ++j) rv[j] = rrn[tn * 8 + j];
  #pragma unroll
  for (int p = 0; p < 2; ++p)
    #pragma unroll
    for (int i = 0; i < 2; ++i) {
      const int o = p * 64 + to * 2 + i;
      const float g2 = (gamma2[o] + 1.0f) * NORM_SCALE_F;
      *reinterpret_cast<float4*>(y + (size_t)o * NTOK + n0 + tn * 8) =
          make_float4(az[p][i][0] * rv[0] * g2, az[p][i][1] * rv[1] * g2,
                      az[p][i][2] * rv[2] * g2, az[p][i][3] * rv[3] * g2);
      *reinterpret_cast<float4*>(y + (size_t)o * NTOK + n0 + tn * 8 + 4) =
          make_float4(az[p][i][4] * rv[4] * g2, az[p][i][5] * rv[5] * g2,
                      az[p][i][6] * rv[6] * g2, az[p][i][7] * rv[7] * g2);
    }
}

// ---------------------------------------------------------------------------
extern "C" void kernel_launch(void* const* d_in, const int* in_sizes, int n_in,
                              void* d_out, int out_size, void* d_ws, size_t ws_size,
                              hipStream_t stream) {
  const float* x      = (const float*)d_in[0];
  const float* gamma1 = (const float*)d_in[1];
  const float* w_qkv  = (const float*)d_in[2];
  const float* mem_kv = (const float*)d_in[3];
  const float* w_out  = (const float*)d_in[4];
  const float* b_out  = (const float*)d_in[5];
  const float* gamma2 = (const float*)d_in[6];
  float* out = (float*)d_out;
  float* ws  = (float*)d_ws;

  // ws layout (floats): total ~4.7 MB
  float* wT  = ws;                   // 128*384       = 49152
  float* Cp  = wT + 49152;           // NB1*4096      = 1048576
  float* Sp  = Cp + 1048576;         // NB1*128       = 32768
  float* Cpp = Sp + 32768;           // 8*4224        = 33792
  float* ctx = Cpp + 33792;          // 4096
  float* W2T = ctx + 4096;           // 128*128       = 16384

  hipLaunchKernelGGL(k0_fold,   dim3(192),     dim3(256), 0, stream, w_qkv, gamma1, wT);
  hipLaunchKernelGGL(k1_kv,     dim3(NB1),     dim3(256), 0, stream, x, wT, Cp, Sp);
  hipLaunchKernelGGL(k3a_reduce,dim3(33, 8),   dim3(256), 0, stream, Cp, Sp, Cpp);
  hipLaunchKernelGGL(k3b1_ctx,  dim3(1),       dim3(256), 0, stream, Cpp, mem_kv, ctx);
  hipLaunchKernelGGL(k3b2_w2,   dim3(8),       dim3(256), 0, stream, ctx, w_out, W2T);
  hipLaunchKernelGGL(k5_out,    dim3(1024),    dim3(256), 0, stream, x, wT, W2T, b_out, gamma2, out);
}

// Round 2
// 204.412 us; speedup vs baseline: 1.5090x; 1.5090x over previous
//
#include <hip/hip_runtime.h>
#include <hip/hip_bf16.h>
#include <cstddef>

// ---------------------------------------------------------------------------
// LinearAttention fused pipeline — round 2: bf16 MFMA for all three GEMMs.
//
//   k/v GEMM + exp + context partials  : k1  (per-wave 32-token slices)
//   partial reduce / ctx / W2 fold     : k3a, k3b1, k3b2 (k3a/k3b1 verbatim
//                                        from the passing fp32 round)
//   q GEMM + softmax + W2 GEMM + norm  : k5
//
// Fragment conventions (mfma_f32_16x16x32_bf16, verified layouts):
//   A: lane l holds A[row = l&15][k = (l>>4)*8 + j], j=0..7
//   B: lane l holds B[k = (l>>4)*8 + j][col = l&15]
//   D: lane l holds D[row = (l>>4)*4 + r][col = l&15], r=0..3
// Weights are pre-packed frag-linear: elem ((rt*4+ks)*64 + lane)*8 + j.
// ---------------------------------------------------------------------------

typedef __attribute__((ext_vector_type(8))) short short8;
typedef __attribute__((ext_vector_type(4))) float f32x4;

static constexpr int   NTOK = 65536;                        // H*W
static constexpr float NORM_SCALE_F = 11.313708498984761f;  // sqrt(128)
static constexpr float SCALE_F      = 0.17677669529663687f; // 1/sqrt(32)

__device__ __forceinline__ unsigned short f2bf(float f) {
  __hip_bfloat16 h = __float2bfloat16(f);
  return *reinterpret_cast<unsigned short*>(&h);
}

// ---------------------------------------------------------------- k0:
// pack q/k/v weights (folded with (gamma1+1)*sqrt(128)) into fragment-linear
// bf16: Wp[m][((rt*4+ks)*64 + lane)*8 + j] = w_qkv[m*128 + rt*16+(lane&15)]
//                                                [ks*32+(lane>>4)*8+j] * g1s
__global__ __launch_bounds__(256) void k0_pack(const float* __restrict__ w_qkv,
                                               const float* __restrict__ gamma1,
                                               unsigned short* __restrict__ Wp) {
  const int id = blockIdx.x * 256 + threadIdx.x;   // < 49152
  const int m = id / 16384, p = id % 16384;
  const int j = p & 7, ln = (p >> 3) & 63, frag = p >> 9;
  const int ks = frag & 3, rt = frag >> 2;
  const int row = rt * 16 + (ln & 15);
  const int c = ks * 32 + (ln >> 4) * 8 + j;
  const float v = w_qkv[(m * 128 + row) * 128 + c] * (gamma1[c] + 1.0f) * NORM_SCALE_F;
  Wp[id] = f2bf(v);
}

// ---------------------------------------------------------------- k1:
// 256 blocks x 512 threads (8 waves); wave w owns tokens n0..n0+31.
// X fragments straight from global; per-token rsqrt via shfl_xor; per-head
// k GEMM -> exp -> LDS, v GEMM -> LDS, context via MFMA. Block-reduce to Cp/Sp.
__global__ __launch_bounds__(512) void k1_kv(const float* __restrict__ x,
                                             const unsigned short* __restrict__ Wkp,
                                             const unsigned short* __restrict__ Wvp,
                                             float* __restrict__ Cp,
                                             float* __restrict__ Sp) {
  __shared__ unsigned short kvs[8][2560];   // per wave: ke[32][40] + v[32][40]
  const int tid = threadIdx.x, wv = tid >> 6, ln = tid & 63;
  const int g4 = ln >> 4, t16 = ln & 15;
  const int n0 = (blockIdx.x * 8 + wv) * 32;
  unsigned short* keb = &kvs[wv][0];
  unsigned short* vb  = &kvs[wv][1280];

  // ---- X fragments + per-token rsqrt(sum x^2)
  short8 xf[2][4];
  float scn[2];
  #pragma unroll
  for (int tg = 0; tg < 2; ++tg) {
    float sq = 0.f;
    #pragma unroll
    for (int ks = 0; ks < 4; ++ks) {
      short8 v;
      #pragma unroll
      for (int j = 0; j < 8; ++j) {
        const float f = x[(size_t)(ks * 32 + g4 * 8 + j) * NTOK + n0 + tg * 16 + t16];
        sq += f * f;
        v[j] = (short)f2bf(f);
      }
      xf[tg][ks] = v;
    }
    sq += __shfl_xor(sq, 16, 64);
    sq += __shfl_xor(sq, 32, 64);
    scn[tg] = rsqrtf(sq);
  }

  f32x4 cacc[4][2][2] = {};     // [h][dt][et] context accumulators
  float sacc[4][2][4] = {};     // [h][rtl][r] denominator partials

  #pragma unroll
  for (int h = 0; h < 4; ++h) {
    // ---- k GEMM (rows 32h..32h+31 of k)
    f32x4 ka[2][2] = {};
    #pragma unroll
    for (int ks = 0; ks < 4; ++ks) {
      const short8 a0 = *reinterpret_cast<const short8*>(Wkp + (((2 * h + 0) * 4 + ks) * 64 + ln) * 8);
      const short8 a1 = *reinterpret_cast<const short8*>(Wkp + (((2 * h + 1) * 4 + ks) * 64 + ln) * 8);
      #pragma unroll
      for (int tg = 0; tg < 2; ++tg) {
        ka[0][tg] = __builtin_amdgcn_mfma_f32_16x16x32_bf16(a0, xf[tg][ks], ka[0][tg], 0, 0, 0);
        ka[1][tg] = __builtin_amdgcn_mfma_f32_16x16x32_bf16(a1, xf[tg][ks], ka[1][tg], 0, 0, 0);
      }
    }
    // ---- exp(k * scn) -> keb, accumulate S
    #pragma unroll
    for (int rtl = 0; rtl < 2; ++rtl)
      #pragma unroll
      for (int tg = 0; tg < 2; ++tg)
        #pragma unroll
        for (int r = 0; r < 4; ++r) {
          const float ke = __expf(ka[rtl][tg][r] * scn[tg]);
          sacc[h][rtl][r] += ke;
          keb[(rtl * 16 + g4 * 4 + r) * 40 + tg * 16 + t16] = f2bf(ke);
        }
    // ---- v GEMM (rows 32h..32h+31 of v)
    f32x4 va[2][2] = {};
    #pragma unroll
    for (int ks = 0; ks < 4; ++ks) {
      const short8 a0 = *reinterpret_cast<const short8*>(Wvp + (((2 * h + 0) * 4 + ks) * 64 + ln) * 8);
      const short8 a1 = *reinterpret_cast<const short8*>(Wvp + (((2 * h + 1) * 4 + ks) * 64 + ln) * 8);
      #pragma unroll
      for (int tg = 0; tg < 2; ++tg) {
        va[0][tg] = __builtin_amdgcn_mfma_f32_16x16x32_bf16(a0, xf[tg][ks], va[0][tg], 0, 0, 0);
        va[1][tg] = __builtin_amdgcn_mfma_f32_16x16x32_bf16(a1, xf[tg][ks], va[1][tg], 0, 0, 0);
      }
    }
    #pragma unroll
    for (int rtl = 0; rtl < 2; ++rtl)
      #pragma unroll
      for (int tg = 0; tg < 2; ++tg)
        #pragma unroll
        for (int r = 0; r < 4; ++r)
          vb[(rtl * 16 + g4 * 4 + r) * 40 + tg * 16 + t16] = f2bf(va[rtl][tg][r] * scn[tg]);

    // ---- context: C[h] += ke · v^T  (K = 32 tokens)
    asm volatile("s_waitcnt lgkmcnt(0)" ::: "memory");   // writes visible
    short8 keA[2], vB[2];
    #pragma unroll
    for (int dt = 0; dt < 2; ++dt)
      keA[dt] = *reinterpret_cast<const short8*>(keb + (dt * 16 + t16) * 40 + g4 * 8);
    #pragma unroll
    for (int et = 0; et < 2; ++et)
      vB[et] = *reinterpret_cast<const short8*>(vb + (et * 16 + t16) * 40 + g4 * 8);
    #pragma unroll
    for (int dt = 0; dt < 2; ++dt)
      #pragma unroll
      for (int et = 0; et < 2; ++et)
        cacc[h][dt][et] = __builtin_amdgcn_mfma_f32_16x16x32_bf16(keA[dt], vB[et], cacc[h][dt][et], 0, 0, 0);
    asm volatile("s_waitcnt lgkmcnt(0)" ::: "memory");   // reads done before reuse
  }

  // ---- S: reduce over the 16 token-lanes
  #pragma unroll
  for (int h = 0; h < 4; ++h)
    #pragma unroll
    for (int rtl = 0; rtl < 2; ++rtl)
      #pragma unroll
      for (int r = 0; r < 4; ++r) {
        float s = sacc[h][rtl][r];
        s += __shfl_xor(s, 1, 64);
        s += __shfl_xor(s, 2, 64);
        s += __shfl_xor(s, 4, 64);
        s += __shfl_xor(s, 8, 64);
        sacc[h][rtl][r] = s;
      }

  // ---- block reduce into LDS (reuse kvs as float buffer), write Cp/Sp
  __syncthreads();
  float* cred = reinterpret_cast<float*>(&kvs[0][0]);    // 4224 floats
  for (int w = 0; w < 8; ++w) {
    if (wv == w) {
      #pragma unroll
      for (int h = 0; h < 4; ++h)
        #pragma unroll
        for (int dt = 0; dt < 2; ++dt)
          #pragma unroll
          for (int et = 0; et < 2; ++et)
            #pragma unroll
            for (int r = 0; r < 4; ++r) {
              const int idx = h * 1024 + (dt * 16 + g4 * 4 + r) * 32 + et * 16 + t16;
              if (w == 0) cred[idx] = cacc[h][dt][et][r];
              else        cred[idx] += cacc[h][dt][et][r];
            }
      if (t16 == 0) {
        #pragma unroll
        for (int h = 0; h < 4; ++h)
          #pragma unroll
          for (int rtl = 0; rtl < 2; ++rtl)
            #pragma unroll
            for (int r = 0; r < 4; ++r) {
              const int si = 4096 + h * 32 + rtl * 16 + g4 * 4 + r;
              if (w == 0) cred[si] = sacc[h][rtl][r];
              else        cred[si] += sacc[h][rtl][r];
            }
      }
    }
    __syncthreads();
  }
  for (int i = tid; i < 4096; i += 512)
    Cp[(size_t)blockIdx.x * 4096 + i] = cred[i];
  if (tid < 128)
    Sp[blockIdx.x * 128 + tid] = cred[4096 + tid];
}

// ---------------------------------------------------------------- k3a:
// reduce partials over 256 blocks in 8 chunks of 32. (verbatim, proven)
__global__ __launch_bounds__(256) void k3a_reduce(const float* __restrict__ Cp,
                                                  const float* __restrict__ Sp,
                                                  float* __restrict__ Cpp) {
  __shared__ float red[256];
  const int t = threadIdx.x;
  const int eg = blockIdx.x;   // 0..32
  const int ch = blockIdx.y;   // 0..7
  const int e = eg * 128 + (t & 127);
  const int half = t >> 7;
  float s = 0.f;
  for (int bb = 0; bb < 16; ++bb) {
    const int b = ch * 32 + half * 16 + bb;
    s += (e < 4096) ? Cp[(size_t)b * 4096 + e] : Sp[b * 128 + (e - 4096)];
  }
  red[t] = s;
  __syncthreads();
  if (t < 128) Cpp[ch * 4224 + eg * 128 + t] = red[t] + red[t + 128];
}

// ---------------------------------------------------------------- k3b1:
// final reduce + memory-kv terms + divide -> ctx[4096] (verbatim, proven)
__global__ __launch_bounds__(256) void k3b1_ctx(const float* __restrict__ Cpp,
                                                const float* __restrict__ mem_kv,
                                                float* __restrict__ ctx) {
  __shared__ float allv[4224];
  const int t = threadIdx.x;
  for (int e = t; e < 4224; e += 256) {
    float s = 0.f;
    #pragma unroll
    for (int c = 0; c < 8; ++c) s += Cpp[c * 4224 + e];
    allv[e] = s;
  }
  __syncthreads();
  for (int e = t; e < 4224; e += 256) {
    if (e < 4096) {
      const int hh = e >> 10, d = (e >> 5) & 31, ev = e & 31;
      float add = 0.f;
      #pragma unroll
      for (int m = 0; m < 4; ++m)
        add += __expf(mem_kv[(hh * 32 + d) * 4 + m]) * mem_kv[512 + (hh * 32 + ev) * 4 + m];
      allv[e] += add;
    } else {
      const int si = e - 4096;
      const int hh = si >> 5, d = si & 31;
      float add = 0.f;
      #pragma unroll
      for (int m = 0; m < 4; ++m) add += __expf(mem_kv[(hh * 32 + d) * 4 + m]);
      allv[e] += add;
    }
  }
  __syncthreads();
  for (int e = t; e < 4096; e += 256)
    ctx[e] = allv[e] / allv[4096 + (e >> 5)];
}

// ---------------------------------------------------------------- k3b2:
// W2[o][hd] = SCALE * sum_e w_out[o][h*32+e] * ctx[h][d][e], packed frag-linear bf16.
__global__ __launch_bounds__(256) void k3b2_w2(const float* __restrict__ ctx,
                                               const float* __restrict__ w_out,
                                               unsigned short* __restrict__ W2p) {
  const int t = threadIdx.x;
  const int hd = t & 127;
  const int og = t >> 7;
  const int hh = hd >> 5, d = hd & 31;
  const int bo = blockIdx.x;  // 0..7
  #pragma unroll
  for (int i = 0; i < 8; ++i) {
    const int o = bo * 16 + og * 8 + i;
    float s = 0.f;
    #pragma unroll
    for (int e = 0; e < 32; ++e)
      s += w_out[o * 128 + hh * 32 + e] * ctx[hh * 1024 + d * 32 + e];
    const int rt = o >> 4, ks = hd >> 5;
    const int lnp = ((hd & 31) >> 3) * 16 + (o & 15);
    const int j = hd & 7;
    W2p[((rt * 4 + ks) * 64 + lnp) * 8 + j] = f2bf(s * SCALE_F);
  }
}

// ---------------------------------------------------------------- k5:
// 256 blocks x 512 threads; wave owns 32 tokens. q GEMM -> softmax over d ->
// qsm to LDS (B-frag-linear) -> W2 GEMM -> +bias -> rmsnorm -> store y.
__global__ __launch_bounds__(512) void k5_out(const float* __restrict__ x,
                                              const unsigned short* __restrict__ Wqp,
                                              const unsigned short* __restrict__ W2p,
                                              const float* __restrict__ b_out,
                                              const float* __restrict__ gamma2,
                                              float* __restrict__ y) {
  __shared__ unsigned short qs[8][4096];
  const int tid = threadIdx.x, wv = tid >> 6, ln = tid & 63;
  const int g4 = ln >> 4, t16 = ln & 15;
  const int n0 = (blockIdx.x * 8 + wv) * 32;
  unsigned short* qb_lds = &qs[wv][0];

  // ---- X fragments + per-token rsqrt (same as k1)
  short8 xf[2][4];
  float scn[2];
  #pragma unroll
  for (int tg = 0; tg < 2; ++tg) {
    float sq = 0.f;
    #pragma unroll
    for (int ks = 0; ks < 4; ++ks) {
      short8 v;
      #pragma unroll
      for (int j = 0; j < 8; ++j) {
        const float f = x[(size_t)(ks * 32 + g4 * 8 + j) * NTOK + n0 + tg * 16 + t16];
        sq += f * f;
        v[j] = (short)f2bf(f);
      }
      xf[tg][ks] = v;
    }
    sq += __shfl_xor(sq, 16, 64);
    sq += __shfl_xor(sq, 32, 64);
    scn[tg] = rsqrtf(sq);
  }

  // ---- q GEMM per head + softmax over d + qsm -> LDS
  #pragma unroll
  for (int h = 0; h < 4; ++h) {
    f32x4 qa[2][2] = {};
    #pragma unroll
    for (int ks = 0; ks < 4; ++ks) {
      const short8 a0 = *reinterpret_cast<const short8*>(Wqp + (((2 * h + 0) * 4 + ks) * 64 + ln) * 8);
      const short8 a1 = *reinterpret_cast<const short8*>(Wqp + (((2 * h + 1) * 4 + ks) * 64 + ln) * 8);
      #pragma unroll
      for (int tg = 0; tg < 2; ++tg) {
        qa[0][tg] = __builtin_amdgcn_mfma_f32_16x16x32_bf16(a0, xf[tg][ks], qa[0][tg], 0, 0, 0);
        qa[1][tg] = __builtin_amdgcn_mfma_f32_16x16x32_bf16(a1, xf[tg][ks], qa[1][tg], 0, 0, 0);
      }
    }
    #pragma unroll
    for (int tg = 0; tg < 2; ++tg) {
      float ev[2][4];
      float s = 0.f;
      #pragma unroll
      for (int rtl = 0; rtl < 2; ++rtl)
        #pragma unroll
        for (int r = 0; r < 4; ++r) {
          ev[rtl][r] = __expf(qa[rtl][tg][r] * scn[tg]);
          s += ev[rtl][r];
        }
      s += __shfl_xor(s, 16, 64);
      s += __shfl_xor(s, 32, 64);
      const float inv = 1.0f / s;
      #pragma unroll
      for (int rtl = 0; rtl < 2; ++rtl)
        #pragma unroll
        for (int r = 0; r < 4; ++r)
          qa[rtl][tg][r] = ev[rtl][r] * inv;
    }
    // write qsm (B-frag-linear): hd = rt*16 + g4*4 + r, tok = tg*16 + t16
    #pragma unroll
    for (int rtl = 0; rtl < 2; ++rtl) {
      const int rt = 2 * h + rtl;
      #pragma unroll
      for (int tg = 0; tg < 2; ++tg) {
        ushort4 w4;
        w4.x = f2bf(qa[rtl][tg][0]);
        w4.y = f2bf(qa[rtl][tg][1]);
        w4.z = f2bf(qa[rtl][tg][2]);
        w4.w = f2bf(qa[rtl][tg][3]);
        const int idxb = ((tg * 4 + (rt >> 1)) * 64 + ((rt & 1) * 2 + (g4 >> 1)) * 16 + t16) * 8 + (g4 & 1) * 4;
        *reinterpret_cast<ushort4*>(&qb_lds[idxb]) = w4;
      }
    }
  }

  asm volatile("s_waitcnt lgkmcnt(0)" ::: "memory");

  // ---- load qsm B-fragments
  short8 qb[2][4];
  #pragma unroll
  for (int tg = 0; tg < 2; ++tg)
    #pragma unroll
    for (int ks = 0; ks < 4; ++ks)
      qb[tg][ks] = *reinterpret_cast<const short8*>(&qb_lds[((tg * 4 + ks) * 64 + ln) * 8]);

  // ---- W2 GEMM: z[o][tok]
  f32x4 z[8][2] = {};
  #pragma unroll
  for (int ks = 0; ks < 4; ++ks)
    #pragma unroll
    for (int rt = 0; rt < 8; ++rt) {
      const short8 a = *reinterpret_cast<const short8*>(W2p + ((rt * 4 + ks) * 64 + ln) * 8);
      #pragma unroll
      for (int tg = 0; tg < 2; ++tg)
        z[rt][tg] = __builtin_amdgcn_mfma_f32_16x16x32_bf16(a, qb[tg][ks], z[rt][tg], 0, 0, 0);
    }

  // ---- + bias, rmsnorm over channels, store
  float ssq[2] = {0.f, 0.f};
  #pragma unroll
  for (int rt = 0; rt < 8; ++rt) {
    const float4 bb = *reinterpret_cast<const float4*>(b_out + rt * 16 + g4 * 4);
    const float barr[4] = {bb.x, bb.y, bb.z, bb.w};
    #pragma unroll
    for (int tg = 0; tg < 2; ++tg)
      #pragma unroll
      for (int r = 0; r < 4; ++r) {
        const float zb = z[rt][tg][r] + barr[r];
        z[rt][tg][r] = zb;
        ssq[tg] += zb * zb;
      }
  }
  float rr[2];
  #pragma unroll
  for (int tg = 0; tg < 2; ++tg) {
    float s = ssq[tg];
    s += __shfl_xor(s, 16, 64);
    s += __shfl_xor(s, 32, 64);
    rr[tg] = rsqrtf(s);
  }
  #pragma unroll
  for (int rt = 0; rt < 8; ++rt) {
    const float4 gg = *reinterpret_cast<const float4*>(gamma2 + rt * 16 + g4 * 4);
    const float garr[4] = {gg.x, gg.y, gg.z, gg.w};
    #pragma unroll
    for (int tg = 0; tg < 2; ++tg)
      #pragma unroll
      for (int r = 0; r < 4; ++r) {
        const int row = rt * 16 + g4 * 4 + r;
        y[(size_t)row * NTOK + n0 + tg * 16 + t16] =
            z[rt][tg][r] * rr[tg] * (garr[r] + 1.0f) * NORM_SCALE_F;
      }
  }
}

// ---------------------------------------------------------------------------
extern "C" void kernel_launch(void* const* d_in, const int* in_sizes, int n_in,
                              void* d_out, int out_size, void* d_ws, size_t ws_size,
                              hipStream_t stream) {
  const float* x      = (const float*)d_in[0];
  const float* gamma1 = (const float*)d_in[1];
  const float* w_qkv  = (const float*)d_in[2];
  const float* mem_kv = (const float*)d_in[3];
  const float* w_out  = (const float*)d_in[4];
  const float* b_out  = (const float*)d_in[5];
  const float* gamma2 = (const float*)d_in[6];
  float* out = (float*)d_out;
  float* ws  = (float*)d_ws;

  // ws layout (floats): packed bf16 weights (32768) + Cp/Sp/Cpp/ctx  (~4.6 MB)
  unsigned short* Wqp = (unsigned short*)ws;     // 16384 ushorts
  unsigned short* Wkp = Wqp + 16384;
  unsigned short* Wvp = Wkp + 16384;
  unsigned short* W2p = Wvp + 16384;
  float* Cp  = ws + 32768;            // 256*4096
  float* Sp  = Cp + 1048576;          // 256*128
  float* Cpp = Sp + 32768;            // 8*4224
  float* ctx = Cpp + 33792;           // 4096

  hipLaunchKernelGGL(k0_pack,  dim3(192),    dim3(256), 0, stream, w_qkv, gamma1, Wqp);
  hipLaunchKernelGGL(k1_kv,    dim3(256),    dim3(512), 0, stream, x, Wkp, Wvp, Cp, Sp);
  hipLaunchKernelGGL(k3a_reduce, dim3(33, 8), dim3(256), 0, stream, Cp, Sp, Cpp);
  hipLaunchKernelGGL(k3b1_ctx, dim3(1),      dim3(256), 0, stream, Cpp, mem_kv, ctx);
  hipLaunchKernelGGL(k3b2_w2,  dim3(8),      dim3(256), 0, stream, ctx, w_out, W2p);
  hipLaunchKernelGGL(k5_out,   dim3(256),    dim3(512), 0, stream, x, Wqp, W2p, b_out, gamma2, out);
}

// Round 3
// 173.467 us; speedup vs baseline: 1.7782x; 1.1784x over previous
//
#include <hip/hip_runtime.h>
#include <hip/hip_bf16.h>
#include <cstddef>

// ---------------------------------------------------------------------------
// LinearAttention — round 3: transpose-free MFMA pipeline.
//
// k1 uses the SWAPPED orientation mfma(A=x^T, B=W) so k^T/v^T come out with
// tokens on the register axis and d on lanes; pairing the two 16-token
// D-frags into one short8 (k-slot bijection k = g4*8 + tg*4 + r <-> token =
// tg*16 + g4*4 + r, identical on A and B) feeds the context MFMA directly —
// no LDS transpose, no fences. Cross-wave reduction via LDS atomicAdd.
// k5 keeps the original orientation (softmax axis on registers) and pairs the
// two 16-row q D-frags per head into a full K=32 B-frag for the W2 GEMM
// (W2p packed to the matching k-mapping hd = h*32 + (j>>2)*16 + g4*4 + (j&3)).
// ---------------------------------------------------------------------------

typedef __attribute__((ext_vector_type(8))) short short8;
typedef __attribute__((ext_vector_type(4))) float f32x4;

static constexpr int   NTOK = 65536;                        // H*W
static constexpr float NORM_SCALE_F = 11.313708498984761f;  // sqrt(128)
static constexpr float SCALE_F      = 0.17677669529663687f; // 1/sqrt(32)

__device__ __forceinline__ unsigned short f2bf(float f) {
  __hip_bfloat16 h = __float2bfloat16(f);
  return *reinterpret_cast<unsigned short*>(&h);
}
__device__ __forceinline__ short sbf(float f) { return (short)f2bf(f); }

// ---------------------------------------------------------------- k0:
// pack q/k/v weights (folded with (gamma1+1)*sqrt(128)) frag-linear bf16:
// Wp[((rt*4+ks)*64 + ln)*8 + j] = w_qkv[rt*16+(ln&15)][ks*32+(ln>>4)*8+j]*g1s
// Serves as A-frag (row=m on ln&15) or B-frag (col=m on ln&15) equally.
__global__ __launch_bounds__(256) void k0_pack(const float* __restrict__ w_qkv,
                                               const float* __restrict__ gamma1,
                                               unsigned short* __restrict__ Wp) {
  const int id = blockIdx.x * 256 + threadIdx.x;   // < 49152
  const int m = id / 16384, p = id % 16384;
  const int j = p & 7, ln = (p >> 3) & 63, frag = p >> 9;
  const int ks = frag & 3, rt = frag >> 2;
  const int row = rt * 16 + (ln & 15);
  const int c = ks * 32 + (ln >> 4) * 8 + j;
  const float v = w_qkv[(m * 128 + row) * 128 + c] * (gamma1[c] + 1.0f) * NORM_SCALE_F;
  Wp[id] = f2bf(v);
}

// ---------------------------------------------------------------- k1:
// 256 blocks x 512 threads (8 waves); wave owns 32 tokens. Swapped GEMMs,
// in-register context, LDS-atomic block reduction -> CpAll[block][4224].
__global__ __launch_bounds__(512) void k1_kv(const float* __restrict__ x,
                                             const unsigned short* __restrict__ Wkp,
                                             const unsigned short* __restrict__ Wvp,
                                             float* __restrict__ CpAll) {
  __shared__ float cred[4224];     // [0,4096): C[h][d][e]; [4096,4224): S[h][d]
  const int tid = threadIdx.x, wv = tid >> 6, ln = tid & 63;
  const int g4 = ln >> 4, t16 = ln & 15;
  const int n0 = (blockIdx.x * 8 + wv) * 32;

  for (int i = tid; i < 4224; i += 512) cred[i] = 0.f;
  __syncthreads();

  // ---- x^T A-frags, pre-normalized bf16 (lane: token = t16, c = ks*32+g4*8+j)
  short8 xf[2][4];
  #pragma unroll
  for (int tg = 0; tg < 2; ++tg) {
    float tmp[4][8];
    float sq = 0.f;
    #pragma unroll
    for (int ks = 0; ks < 4; ++ks)
      #pragma unroll
      for (int j = 0; j < 8; ++j) {
        const float f = x[(size_t)(ks * 32 + g4 * 8 + j) * NTOK + n0 + tg * 16 + t16];
        tmp[ks][j] = f;
        sq += f * f;
      }
    sq += __shfl_xor(sq, 16, 64);
    sq += __shfl_xor(sq, 32, 64);
    const float s = rsqrtf(sq);
    #pragma unroll
    for (int ks = 0; ks < 4; ++ks) {
      short8 v;
      #pragma unroll
      for (int j = 0; j < 8; ++j) v[j] = sbf(tmp[ks][j] * s);
      xf[tg][ks] = v;
    }
  }

  #pragma unroll
  for (int h = 0; h < 4; ++h) {
    // ---- k^T GEMM: D[token][d]  (A = x^T, B = Wk)
    f32x4 ka[2][2] = {};   // [mt][tg]
    #pragma unroll
    for (int ks = 0; ks < 4; ++ks) {
      const short8 b0 = *reinterpret_cast<const short8*>(Wkp + (((2 * h + 0) * 4 + ks) * 64 + ln) * 8);
      const short8 b1 = *reinterpret_cast<const short8*>(Wkp + (((2 * h + 1) * 4 + ks) * 64 + ln) * 8);
      #pragma unroll
      for (int tg = 0; tg < 2; ++tg) {
        ka[0][tg] = __builtin_amdgcn_mfma_f32_16x16x32_bf16(xf[tg][ks], b0, ka[0][tg], 0, 0, 0);
        ka[1][tg] = __builtin_amdgcn_mfma_f32_16x16x32_bf16(xf[tg][ks], b1, ka[1][tg], 0, 0, 0);
      }
    }
    // ---- exp -> paired A-frag (j = tg*4+r), S partial -> LDS atomic
    short8 keA[2];
    #pragma unroll
    for (int mt = 0; mt < 2; ++mt) {
      float sl = 0.f;
      short8 u;
      #pragma unroll
      for (int tg = 0; tg < 2; ++tg)
        #pragma unroll
        for (int r = 0; r < 4; ++r) {
          const float e = __expf(ka[mt][tg][r]);
          sl += e;
          u[tg * 4 + r] = sbf(e);
        }
      keA[mt] = u;
      sl += __shfl_xor(sl, 16, 64);
      sl += __shfl_xor(sl, 32, 64);
      if (g4 == 0) atomicAdd(&cred[4096 + h * 32 + mt * 16 + t16], sl);
    }
    // ---- v^T GEMM
    f32x4 va[2][2] = {};
    #pragma unroll
    for (int ks = 0; ks < 4; ++ks) {
      const short8 b0 = *reinterpret_cast<const short8*>(Wvp + (((2 * h + 0) * 4 + ks) * 64 + ln) * 8);
      const short8 b1 = *reinterpret_cast<const short8*>(Wvp + (((2 * h + 1) * 4 + ks) * 64 + ln) * 8);
      #pragma unroll
      for (int tg = 0; tg < 2; ++tg) {
        va[0][tg] = __builtin_amdgcn_mfma_f32_16x16x32_bf16(xf[tg][ks], b0, va[0][tg], 0, 0, 0);
        va[1][tg] = __builtin_amdgcn_mfma_f32_16x16x32_bf16(xf[tg][ks], b1, va[1][tg], 0, 0, 0);
      }
    }
    short8 vB[2];
    #pragma unroll
    for (int et = 0; et < 2; ++et) {
      short8 u;
      #pragma unroll
      for (int tg = 0; tg < 2; ++tg)
        #pragma unroll
        for (int r = 0; r < 4; ++r)
          u[tg * 4 + r] = sbf(va[et][tg][r]);
      vB[et] = u;
    }
    // ---- context MFMA (K=32 over paired tokens) + atomic drain
    #pragma unroll
    for (int dt = 0; dt < 2; ++dt)
      #pragma unroll
      for (int et = 0; et < 2; ++et) {
        f32x4 zc = {0.f, 0.f, 0.f, 0.f};
        zc = __builtin_amdgcn_mfma_f32_16x16x32_bf16(keA[dt], vB[et], zc, 0, 0, 0);
        #pragma unroll
        for (int r = 0; r < 4; ++r)
          atomicAdd(&cred[h * 1024 + (dt * 16 + g4 * 4 + r) * 32 + et * 16 + t16], zc[r]);
      }
  }

  __syncthreads();
  for (int i = tid; i < 4224; i += 512)
    CpAll[(size_t)blockIdx.x * 4224 + i] = cred[i];
}

// ---------------------------------------------------------------- k3a:
// reduce 256 block-partials (4224 each) in 8 chunks of 32.
__global__ __launch_bounds__(256) void k3a_reduce(const float* __restrict__ CpAll,
                                                  float* __restrict__ Cpp) {
  __shared__ float red[256];
  const int t = threadIdx.x;
  const int eg = blockIdx.x;   // 0..32
  const int ch = blockIdx.y;   // 0..7
  const int e = eg * 128 + (t & 127);   // < 4224 exactly (33*128)
  const int half = t >> 7;
  float s = 0.f;
  for (int bb = 0; bb < 16; ++bb) {
    const int b = ch * 32 + half * 16 + bb;
    s += CpAll[(size_t)b * 4224 + e];
  }
  red[t] = s;
  __syncthreads();
  if (t < 128) Cpp[ch * 4224 + eg * 128 + t] = red[t] + red[t + 128];
}

// ---------------------------------------------------------------- k3b1:
// final reduce + memory-kv terms + divide -> ctx[4096] (proven)
__global__ __launch_bounds__(256) void k3b1_ctx(const float* __restrict__ Cpp,
                                                const float* __restrict__ mem_kv,
                                                float* __restrict__ ctx) {
  __shared__ float allv[4224];
  const int t = threadIdx.x;
  for (int e = t; e < 4224; e += 256) {
    float s = 0.f;
    #pragma unroll
    for (int c = 0; c < 8; ++c) s += Cpp[c * 4224 + e];
    allv[e] = s;
  }
  __syncthreads();
  for (int e = t; e < 4224; e += 256) {
    if (e < 4096) {
      const int hh = e >> 10, d = (e >> 5) & 31, ev = e & 31;
      float add = 0.f;
      #pragma unroll
      for (int m = 0; m < 4; ++m)
        add += __expf(mem_kv[(hh * 32 + d) * 4 + m]) * mem_kv[512 + (hh * 32 + ev) * 4 + m];
      allv[e] += add;
    } else {
      const int si = e - 4096;
      const int hh = si >> 5, d = si & 31;
      float add = 0.f;
      #pragma unroll
      for (int m = 0; m < 4; ++m) add += __expf(mem_kv[(hh * 32 + d) * 4 + m]);
      allv[e] += add;
    }
  }
  __syncthreads();
  for (int e = t; e < 4096; e += 256)
    ctx[e] = allv[e] / allv[4096 + (e >> 5)];
}

// ---------------------------------------------------------------- k3b2:
// W2p A-frags: frag (ot,h), elem j: W2[ot*16+(ln&15)][h*32+(j>>2)*16+(ln>>4)*4+(j&3)]
// where W2[o][h*32+d] = SCALE * sum_e w_out[o][h*32+e] * ctx[h][d][e].
__global__ __launch_bounds__(256) void k3b2_w2(const float* __restrict__ ctx,
                                               const float* __restrict__ w_out,
                                               unsigned short* __restrict__ W2p) {
  const int base = (blockIdx.x * 256 + threadIdx.x) * 8;  // 2048 threads * 8 = 16384
  const int ln = (base >> 3) & 63;
  const int frag = base >> 9;          // 0..31
  const int h = frag & 3, ot = frag >> 2;
  const int o = ot * 16 + (ln & 15);
  float wrow[32];
  #pragma unroll
  for (int e = 0; e < 32; ++e) wrow[e] = w_out[o * 128 + h * 32 + e];
  short8 out8;
  #pragma unroll
  for (int j = 0; j < 8; ++j) {
    const int d = (j >> 2) * 16 + ((ln >> 4) << 2) + (j & 3);
    float s = 0.f;
    #pragma unroll
    for (int e = 0; e < 32; ++e)
      s += wrow[e] * ctx[h * 1024 + d * 32 + e];
    out8[j] = sbf(s * SCALE_F);
  }
  *reinterpret_cast<short8*>(W2p + base) = out8;
}

// ---------------------------------------------------------------- k5:
// 512 blocks x 256 threads (4 waves); wave owns 32 tokens. NO LDS.
// q GEMM (orig orientation) -> softmax over d -> paired B-frags -> W2 GEMM
// -> +bias -> rmsnorm -> store y.
__global__ __launch_bounds__(256) void k5_out(const float* __restrict__ x,
                                              const unsigned short* __restrict__ Wqp,
                                              const unsigned short* __restrict__ W2p,
                                              const float* __restrict__ b_out,
                                              const float* __restrict__ gamma2,
                                              float* __restrict__ y) {
  const int tid = threadIdx.x, wv = tid >> 6, ln = tid & 63;
  const int g4 = ln >> 4, t16 = ln & 15;
  const int n0 = (blockIdx.x * 4 + wv) * 32;

  // ---- x B-frags (lane: c = ks*32+g4*8+j, token = t16), pre-normalized bf16
  short8 xf[2][4];
  #pragma unroll
  for (int tg = 0; tg < 2; ++tg) {
    float tmp[4][8];
    float sq = 0.f;
    #pragma unroll
    for (int ks = 0; ks < 4; ++ks)
      #pragma unroll
      for (int j = 0; j < 8; ++j) {
        const float f = x[(size_t)(ks * 32 + g4 * 8 + j) * NTOK + n0 + tg * 16 + t16];
        tmp[ks][j] = f;
        sq += f * f;
      }
    sq += __shfl_xor(sq, 16, 64);
    sq += __shfl_xor(sq, 32, 64);
    const float s = rsqrtf(sq);
    #pragma unroll
    for (int ks = 0; ks < 4; ++ks) {
      short8 v;
      #pragma unroll
      for (int j = 0; j < 8; ++j) v[j] = sbf(tmp[ks][j] * s);
      xf[tg][ks] = v;
    }
  }

  // ---- q GEMM per head + softmax over d -> paired B-frags qB[h][tg]
  short8 qB[4][2];
  #pragma unroll
  for (int h = 0; h < 4; ++h) {
    f32x4 qa[2][2] = {};   // [rtl][tg]; lane: hd = h*32+rtl*16+g4*4+r, tok = t16
    #pragma unroll
    for (int ks = 0; ks < 4; ++ks) {
      const short8 a0 = *reinterpret_cast<const short8*>(Wqp + (((2 * h + 0) * 4 + ks) * 64 + ln) * 8);
      const short8 a1 = *reinterpret_cast<const short8*>(Wqp + (((2 * h + 1) * 4 + ks) * 64 + ln) * 8);
      #pragma unroll
      for (int tg = 0; tg < 2; ++tg) {
        qa[0][tg] = __builtin_amdgcn_mfma_f32_16x16x32_bf16(a0, xf[tg][ks], qa[0][tg], 0, 0, 0);
        qa[1][tg] = __builtin_amdgcn_mfma_f32_16x16x32_bf16(a1, xf[tg][ks], qa[1][tg], 0, 0, 0);
      }
    }
    #pragma unroll
    for (int tg = 0; tg < 2; ++tg) {
      float ev[2][4];
      float ss = 0.f;
      #pragma unroll
      for (int rtl = 0; rtl < 2; ++rtl)
        #pragma unroll
        for (int r = 0; r < 4; ++r) {
          ev[rtl][r] = __expf(qa[rtl][tg][r]);
          ss += ev[rtl][r];
        }
      ss += __shfl_xor(ss, 16, 64);
      ss += __shfl_xor(ss, 32, 64);
      const float inv = 1.0f / ss;
      short8 u;
      #pragma unroll
      for (int rtl = 0; rtl < 2; ++rtl)
        #pragma unroll
        for (int r = 0; r < 4; ++r)
          u[rtl * 4 + r] = sbf(ev[rtl][r] * inv);
      qB[h][tg] = u;   // B-frag slot j: hd = h*32+(j>>2)*16+g4*4+(j&3)
    }
  }

  // ---- W2 GEMM: z[o][tok]
  f32x4 z[8][2] = {};
  #pragma unroll
  for (int h = 0; h < 4; ++h)
    #pragma unroll
    for (int ot = 0; ot < 8; ++ot) {
      const short8 a = *reinterpret_cast<const short8*>(W2p + ((ot * 4 + h) * 64 + ln) * 8);
      #pragma unroll
      for (int tg = 0; tg < 2; ++tg)
        z[ot][tg] = __builtin_amdgcn_mfma_f32_16x16x32_bf16(a, qB[h][tg], z[ot][tg], 0, 0, 0);
    }

  // ---- + bias, rmsnorm over channels, store
  float ssq[2] = {0.f, 0.f};
  #pragma unroll
  for (int ot = 0; ot < 8; ++ot) {
    const float4 bb = *reinterpret_cast<const float4*>(b_out + ot * 16 + g4 * 4);
    const float barr[4] = {bb.x, bb.y, bb.z, bb.w};
    #pragma unroll
    for (int tg = 0; tg < 2; ++tg)
      #pragma unroll
      for (int r = 0; r < 4; ++r) {
        const float zb = z[ot][tg][r] + barr[r];
        z[ot][tg][r] = zb;
        ssq[tg] += zb * zb;
      }
  }
  float rr[2];
  #pragma unroll
  for (int tg = 0; tg < 2; ++tg) {
    float s = ssq[tg];
    s += __shfl_xor(s, 16, 64);
    s += __shfl_xor(s, 32, 64);
    rr[tg] = rsqrtf(s);
  }
  #pragma unroll
  for (int ot = 0; ot < 8; ++ot) {
    const float4 gg = *reinterpret_cast<const float4*>(gamma2 + ot * 16 + g4 * 4);
    const float garr[4] = {gg.x, gg.y, gg.z, gg.w};
    #pragma unroll
    for (int tg = 0; tg < 2; ++tg)
      #pragma unroll
      for (int r = 0; r < 4; ++r) {
        const int row = ot * 16 + g4 * 4 + r;
        y[(size_t)row * NTOK + n0 + tg * 16 + t16] =
            z[ot][tg][r] * rr[tg] * (garr[r] + 1.0f) * NORM_SCALE_F;
      }
  }
}

// ---------------------------------------------------------------------------
extern "C" void kernel_launch(void* const* d_in, const int* in_sizes, int n_in,
                              void* d_out, int out_size, void* d_ws, size_t ws_size,
                              hipStream_t stream) {
  const float* x      = (const float*)d_in[0];
  const float* gamma1 = (const float*)d_in[1];
  const float* w_qkv  = (const float*)d_in[2];
  const float* mem_kv = (const float*)d_in[3];
  const float* w_out  = (const float*)d_in[4];
  const float* b_out  = (const float*)d_in[5];
  const float* gamma2 = (const float*)d_in[6];
  float* out = (float*)d_out;
  float* ws  = (float*)d_ws;

  // ws layout: 4 packed weight blocks (65536 shorts = 32768 float-slots),
  // CpAll 256*4224, Cpp 8*4224, ctx 4096  => 1,152,000 floats = 4.6 MB
  unsigned short* Wqp = (unsigned short*)ws;     // 16384 ushorts
  unsigned short* Wkp = Wqp + 16384;
  unsigned short* Wvp = Wkp + 16384;
  unsigned short* W2p = Wvp + 16384;
  float* CpAll = ws + 32768;            // 256*4224
  float* Cpp   = CpAll + 1081344;       // 8*4224
  float* ctx   = Cpp + 33792;           // 4096

  hipLaunchKernelGGL(k0_pack,    dim3(192),    dim3(256), 0, stream, w_qkv, gamma1, Wqp);
  hipLaunchKernelGGL(k1_kv,      dim3(256),    dim3(512), 0, stream, x, Wkp, Wvp, CpAll);
  hipLaunchKernelGGL(k3a_reduce, dim3(33, 8),  dim3(256), 0, stream, CpAll, Cpp);
  hipLaunchKernelGGL(k3b1_ctx,   dim3(1),      dim3(256), 0, stream, Cpp, mem_kv, ctx);
  hipLaunchKernelGGL(k3b2_w2,    dim3(8),      dim3(256), 0, stream, ctx, w_out, W2p);
  hipLaunchKernelGGL(k5_out,     dim3(512),    dim3(256), 0, stream, x, Wqp, W2p, b_out, gamma2, out);
}